// Round 9
// baseline (274.406 us; speedup 1.0000x reference)
//
#include <hip/hip_runtime.h>

#define NPOS 21824          // 16384+4096+1024+256+64 positions per image
#define MINS 0.05f
#define CAP  4096           // per-image candidate-list capacity
#define THETA 0.89f         // perf heuristic only — exact fallback if violated

struct Ptrs { const float* cls[5]; const float* reg[5]; const float* ctr[5]; };

__device__ __forceinline__ float sigf(float x){ return 1.0f/(1.0f+expf(-x)); }

__device__ __forceinline__ unsigned long long mkkey(unsigned int bits, int p){
    return ((unsigned long long)bits << 16) | (unsigned)(65535 - p);
}

// exact reference box math: trunc-toward-zero then one-sided clamps
__device__ float4 decode_box(const Ptrs& P, int img, int p){
    int lvl, base, lw, stride;
    if (p < 16384)      { lvl=0; base=0;     lw=7; stride=8;   }
    else if (p < 20480) { lvl=1; base=16384; lw=6; stride=16;  }
    else if (p < 21504) { lvl=2; base=20480; lw=5; stride=32;  }
    else if (p < 21760) { lvl=3; base=21504; lw=4; stride=64;  }
    else                { lvl=4; base=21760; lw=3; stride=128; }
    int pl = p - base;
    int h = pl >> lw, w = pl & ((1<<lw)-1);
    long long lidx = (long long)img*(1<<(2*lw)) + pl;
    float4 rg = ((const float4*)P.reg[lvl])[lidx];
    float x = (w + 0.5f)*(float)stride;
    float y = (h + 0.5f)*(float)stride;
    int ix1 = (int)(x - expf(rg.x));
    int iy1 = (int)(y - expf(rg.y));
    int ix2 = (int)(x + expf(rg.z));
    int iy2 = (int)(y + expf(rg.w));
    ix1 = max(ix1,0); iy1 = max(iy1,0);
    ix2 = min(ix2,1023); iy2 = min(iy2,1023);
    return make_float4((float)ix1,(float)iy1,(float)ix2,(float)iy2);
}

// --- Kernel A: score/class per position + threshold-append candidate list ---
__global__ __launch_bounds__(256) void k_score(Ptrs P, float* scoreAll, int* clsAll,
                                               unsigned long long* gList, int* gcount)
{
    int img  = blockIdx.y;
    int blk  = blockIdx.x;           // [0,341)
    int tid  = threadIdx.x;
    int posb = tid >> 2;
    int l    = tid & 3;
    int p    = blk*64 + posb;
    int lvl, base, lw;
    if (blk < 256)      { lvl=0; base=0;     lw=7; }
    else if (blk < 320) { lvl=1; base=16384; lw=6; }
    else if (blk < 336) { lvl=2; base=20480; lw=5; }
    else if (blk < 340) { lvl=3; base=21504; lw=4; }
    else                { lvl=4; base=21760; lw=3; }
    int pl = p - base;
    long long lidx = (long long)img*(1<<(2*lw)) + pl;

    const float4* c4 = (const float4*)(P.cls[lvl] + lidx*80);
    float mx = -3.4e38f; int mi = 0;
#pragma unroll
    for (int j = 0; j < 5; ++j) {
        int k = j*4 + l;
        float4 v = c4[k];
        int cb = k*4;
        if (v.x > mx){mx=v.x; mi=cb;}
        if (v.y > mx){mx=v.y; mi=cb+1;}
        if (v.z > mx){mx=v.z; mi=cb+2;}
        if (v.w > mx){mx=v.w; mi=cb+3;}
    }
#pragma unroll
    for (int d = 1; d < 4; d <<= 1) {
        float omx = __shfl_xor(mx, d);
        int   omi = __shfl_xor(mi, d);
        if (omx > mx || (omx == mx && omi < mi)) { mx = omx; mi = omi; }
    }
    if (l == 0) {
        float ct = P.ctr[lvl][lidx];
        float sc = sqrtf(sigf(mx)*sigf(ct));          // sigmoid(max)==max(sigmoid)
        int o = img*NPOS + p;
        scoreAll[o] = sc;
        clsAll[o]   = mi;
        if (sc > THETA) {
            int t = atomicAdd(&gcount[img], 1);
            if (t < CAP)
                gList[(long long)img*CAP + t] = mkkey(__float_as_uint(sc), p);
        }
    }
}

// ---- Kernel B: top-256 from list + IoU-bitmatrix greedy NMS (8 blocks) -----
// key=(score_bits<<16)|(65535-p): desc key == desc score, ties lower p ==
// reference concat-order tie-break. Image top-256 by key == union top-256.
// If M=count(score>THETA) >= 256, list provably contains the image top-256.
__global__ __launch_bounds__(256) void k_nms7(Ptrs P, const float* scoreAll,
                                              const int* clsAll,
                                              const unsigned long long* gList,
                                              const int* gcount, float* out)
{
    __shared__ unsigned long long lKey[CAP];
    __shared__ unsigned long long sorted[256], selA[256];
    __shared__ float4 sBox[256];
    __shared__ float  sCls[256], sA[256];
    __shared__ unsigned long long supMask[1024];      // 256 rows x 4; fallback: red
    __shared__ int eq[256];
    __shared__ int wsum[4];
    __shared__ unsigned int shPref;
    __shared__ int tick, eqn, shNa, shFB, supFlag, cntR;
    __shared__ unsigned long long lastK;
    __shared__ int    accList[100];
    __shared__ float4 accB[100];
    __shared__ float  accA[100];

    int img = blockIdx.x, tid = threadIdx.x;
    int lane = tid & 63, wv = tid >> 6;
    const unsigned int* gs = (const unsigned int*)scoreAll + (long long)img*NPOS;
    const int* gCls = clsAll + (long long)img*NPOS;

    int M = gcount[img];
    bool useL = (M >= 256 && M <= CAP);

    if (useL) {
        for (int i = tid; i < M; i += 256)
            lKey[i] = gList[(long long)img*CAP + i];
        __syncthreads();
        // rank-by-counting -> sorted[0..255] (keys unique)
        int nk = (M + 255) >> 8;
        for (int q = 0; q < nk; ++q) {
            int idx = tid + q*256;
            if (idx < M) {
                unsigned long long k = lKey[idx];
                int r = 0;
                for (int j = 0; j < M; ++j) r += (lKey[j] > k);  // broadcast reads
                if (r < 256) sorted[r] = k;
            }
        }
        __syncthreads();
    } else {
        // ---- exact fallback: 32-step count bit-search over global scores ----
        if (tid == 0) shPref = 0;
        __syncthreads();
        for (int bit = 31; bit >= 0; --bit) {
            unsigned int t = shPref | (1u << bit);
            int c = 0;
            for (int i = tid; i < NPOS; i += 256) c += (gs[i] >= t);
#pragma unroll
            for (int off = 1; off < 64; off <<= 1) c += __shfl_xor(c, off);
            if (lane == 0) wsum[wv] = c;
            __syncthreads();
            if (tid == 0 && (wsum[0]+wsum[1]+wsum[2]+wsum[3]) >= 256) shPref = t;
            __syncthreads();
        }
        unsigned int kth = shPref;
        if (tid == 0) { tick = 0; eqn = 0; }
        __syncthreads();
        for (int i = tid; i < NPOS; i += 256) {
            unsigned int b = gs[i];
            if (b > kth)       { int t = atomicAdd(&tick, 1); selA[t] = mkkey(b, i); }
            else if (b == kth) { int t = atomicAdd(&eqn, 1); if (t < 256) eq[t] = i; }
        }
        __syncthreads();
        int m = eqn, nG = tick, need = 256 - nG;
        if (m <= 256) {
            for (int q = tid; q < m; q += 256) {
                int pq = eq[q], r = 0;
                for (int j = 0; j < m; ++j) r += (eq[j] < pq);
                if (r < need) selA[nG + r] = mkkey(kth, pq);
            }
        } else if (tid == 0) {
            int cnt = 0;
            for (int i = 0; i < NPOS && cnt < need; ++i)
                if (gs[i] == kth) { selA[nG + cnt] = mkkey(kth, i); ++cnt; }
        }
        __syncthreads();
        {
            unsigned long long k = selA[tid];
            int r = 0;
            for (int j = 0; j < 256; ++j) r += (selA[j] > k);
            sorted[r] = k;
        }
        __syncthreads();
    }

    // ---- gather cls, decode boxes for the 256 ----
    {
        int p = 65535 - (int)(sorted[tid] & 0xFFFF);
        float4 b = decode_box(P, img, p);
        sBox[tid] = b;
        sCls[tid] = (float)gCls[p];
        sA[tid]   = (b.z - b.x)*(b.w - b.y);
    }
    __syncthreads();

    // ---- 256x256 suppression bitmatrix ----
    {
        float4 bt = sBox[tid]; float at = sA[tid];
        unsigned long long w0=0, w1=0, w2=0, w3=0;
        for (int j = 0; j < 256; ++j) {
            float4 bj = sBox[j];                       // broadcast LDS read
            float iw = fmaxf(fminf(bt.z,bj.z)-fmaxf(bt.x,bj.x),0.f);
            float ih = fmaxf(fminf(bt.w,bj.w)-fmaxf(bt.y,bj.y),0.f);
            float in_ = iw*ih;
            bool sup = (j != tid) && (in_/(at + sA[j] - in_ + 1e-12f) > 0.6f);
            unsigned long long bit = sup ? (1ull << (j & 63)) : 0ull;
            if (j < 64) w0 |= bit; else if (j < 128) w1 |= bit;
            else if (j < 192) w2 |= bit; else w3 |= bit;
        }
        supMask[tid*4+0]=w0; supMask[tid*4+1]=w1;
        supMask[tid*4+2]=w2; supMask[tid*4+3]=w3;
    }
    __syncthreads();

    // ---- chunked-register greedy scan on wave 0 (== sequential NMS) ----
    // Rows 1-per-lane per 64-chunk; accept mask uniform in 4 VGPRs; decisions
    // broadcast via shfl. All breaks are wave-uniform.
    if (tid < 64) {
        unsigned long long a0=0, a1=0, a2=0, a3=0;
        int na = 0, fb = 1;
        for (int c = 0; c < 4 && fb; ++c) {
            int idx = c*64 + lane;
            unsigned long long r0 = supMask[idx*4+0];
            unsigned long long r1 = supMask[idx*4+1];
            unsigned long long r2 = supMask[idx*4+2];
            unsigned long long r3 = supMask[idx*4+3];
            float scl = __uint_as_float((unsigned int)(sorted[idx] >> 16));
            for (int i = 0; i < 64; ++i) {
                float scI = __shfl(scl, i);
                if (!(scI > MINS)) { fb = 0; break; }
                bool supMine = ((r0&a0)|(r1&a1)|(r2&a2)|(r3&a3)) != 0ull;
                int supI = __shfl((int)supMine, i);
                if (!supI) {
                    int gi = c*64 + i;
                    if (gi < 64) a0 |= 1ull<<gi; else if (gi < 128) a1 |= 1ull<<(gi-64);
                    else if (gi < 192) a2 |= 1ull<<(gi-128); else a3 |= 1ull<<(gi-192);
                    if (lane == 0) accList[na] = gi;
                    ++na;
                    if (na == 100) { fb = 0; break; }
                }
            }
        }
        if (lane == 0) { shNa = na; shFB = (fb && na < 100) ? 1 : 0; lastK = sorted[255]; }
    }
    __syncthreads();

    int na = shNa;
    float* outS = out + img*100;
    float* outC = out + 800 + img*100;
    float* outB = out + 1600 + img*400;
    if (tid < 100) {
        if (tid < na) {
            int ix = accList[tid];
            outS[tid] = __uint_as_float((unsigned int)(sorted[ix] >> 16));
            outC[tid] = sCls[ix];
            float4 b = sBox[ix];
            outB[4*tid]=b.x; outB[4*tid+1]=b.y; outB[4*tid+2]=b.z; outB[4*tid+3]=b.w;
            accB[tid] = b; accA[tid] = sA[ix];
        } else {
            outS[tid] = -1.f; outC[tid] = -1.f;
            outB[4*tid]=-1.f; outB[4*tid+1]=-1.f; outB[4*tid+2]=-1.f; outB[4*tid+3]=-1.f;
        }
    }
    __syncthreads();
    if (!shFB) return;

    // ---- exact slow fallback: top-256 exhausted (never on real data) ----
    unsigned long long* red = supMask;
    while (true) {
        unsigned long long lk = lastK, best = 0;
        for (int i = tid; i < NPOS; i += 256) {
            unsigned long long k = mkkey(gs[i], i);
            if (k < lk && k > best) best = k;
        }
        red[tid] = best;
        __syncthreads();
        if (tid == 0) {
            unsigned long long b = 0;
            for (int j = 0; j < 256; ++j) if (red[j] > b) b = red[j];
            red[0] = b;
        }
        __syncthreads();
        best = red[0];
        __syncthreads();
        if (best == 0ull) break;
        float sc = __uint_as_float((unsigned int)(best >> 16));
        if (!(sc > MINS)) break;
        int p = 65535 - (int)(best & 0xFFFF);
        int lvl = p < 16384 ? 0 : p < 20480 ? 1 : p < 21504 ? 2 : p < 21760 ? 3 : 4;
        bool elig = true;
        if (lvl < 3) {                   // union membership: level-rank < 1000
            int base = lvl == 0 ? 0 : (lvl == 1 ? 16384 : 20480);
            int Nl   = lvl == 0 ? 16384 : (lvl == 1 ? 4096 : 1024);
            if (tid == 0) cntR = 0;
            __syncthreads();
            int c = 0;
            for (int q = tid; q < Nl; q += 256)
                if (mkkey(gs[base+q], base+q) > best) ++c;
            atomicAdd(&cntR, c);
            __syncthreads();
            elig = (cntR < 1000);
        }
        if (elig) {
            float4 nb = decode_box(P, img, p);
            float nA = (nb.z - nb.x)*(nb.w - nb.y);
            if (tid == 0) supFlag = 0;
            __syncthreads();
            if (tid < shNa) {
                float4 ab = accB[tid];
                float iw = fmaxf(fminf(nb.z,ab.z)-fmaxf(nb.x,ab.x),0.f);
                float ih = fmaxf(fminf(nb.w,ab.w)-fmaxf(nb.y,ab.y),0.f);
                float in_ = iw*ih;
                if (in_/(nA + accA[tid] - in_ + 1e-12f) > 0.6f) atomicOr(&supFlag, 1);
            }
            __syncthreads();
            if (!supFlag) {
                if (tid == 0) {
                    int k2 = shNa;
                    outS[k2] = sc; outC[k2] = (float)gCls[p];
                    outB[4*k2]=nb.x; outB[4*k2+1]=nb.y; outB[4*k2+2]=nb.z; outB[4*k2+3]=nb.w;
                    accB[k2] = nb; accA[k2] = nA; shNa = k2 + 1;
                }
                __syncthreads();
                if (shNa >= 100) break;
            }
        }
        if (tid == 0) lastK = best;
        __syncthreads();
    }
}

extern "C" void kernel_launch(void* const* d_in, const int* in_sizes, int n_in,
                              void* d_out, int out_size, void* d_ws, size_t ws_size,
                              hipStream_t stream) {
    Ptrs P;
    bool interleaved = (in_sizes[1] == 8 * 128 * 128 * 4);
    for (int i = 0; i < 5; ++i) {
        if (interleaved) {
            P.cls[i] = (const float*)d_in[3*i];
            P.reg[i] = (const float*)d_in[3*i + 1];
            P.ctr[i] = (const float*)d_in[3*i + 2];
        } else {
            P.cls[i] = (const float*)d_in[i];
            P.reg[i] = (const float*)d_in[5 + i];
            P.ctr[i] = (const float*)d_in[10 + i];
        }
    }

    char* wbase = (char*)d_ws;
    size_t off = 0;
    auto alloc = [&](size_t bytes) -> void* {
        void* r = wbase + off;
        off += (bytes + 255) & ~(size_t)255;
        return r;
    };
    float*              scoreAll = (float*)alloc((size_t)8 * NPOS * 4);
    int*                clsAll   = (int*)alloc((size_t)8 * NPOS * 4);
    unsigned long long* gList    = (unsigned long long*)alloc((size_t)8 * CAP * 8);
    int*                gcount   = (int*)alloc(256);

    hipMemsetAsync(gcount, 0, 256, stream);

    dim3 gA(341, 8);   // 341*64 = 21824 positions, level boundaries block-aligned
    k_score<<<gA, 256, 0, stream>>>(P, scoreAll, clsAll, gList, gcount);
    k_nms7 <<<8,  256, 0, stream>>>(P, scoreAll, clsAll, gList, gcount,
                                    (float*)d_out);
}